// Round 10
// baseline (17.556 us; speedup 1.0000x reference)
//
#include <hip/hip_runtime.h>
#include <math.h>

#define NQ    12
#define DIM   4096
#define BATCH 512
#define NBLK  256      // 2 elements per block, software-pipelined

// float2-granular padded LDS index: +2 float2 per 16 (r2-verified bank math).
#define PAD2(i) ((i) + 2 * ((i) >> 4))

// One butterfly level over the 16 register-resident float2 amplitudes.
// q = gate index (acts on state bit 11-q), J = local register bit.
#define LEVEL(q, J) do {                                                    \
    const float4 GA = *(const float4*)&g[q][0];                             \
    const float4 GB = *(const float4*)&g[q][4];                             \
    _Pragma("unroll")                                                       \
    for (int p = 0; p < 8; ++p) {                                           \
        const int r0 = ((p >> (J)) << ((J) + 1)) | (p & ((1 << (J)) - 1));  \
        const int r1 = r0 | (1 << (J));                                     \
        const float ar = x[r0].x, ai = x[r0].y;                             \
        const float br = x[r1].x, bi = x[r1].y;                             \
        x[r0].x = GA.x * ar - GA.y * ai + GA.z * br - GA.w * bi;            \
        x[r0].y = GA.x * ai + GA.y * ar + GA.z * bi + GA.w * br;            \
        x[r1].x = GB.x * ar - GB.y * ai + GB.z * br - GB.w * bi;            \
        x[r1].y = GB.x * ai + GB.y * ar + GB.z * bi + GB.w * br;            \
    }                                                                       \
} while (0)

#define UNPACK(v0, v1, v2, v3, w0, w1, w2, w3) do {                         \
    x[ 0] = make_float2(v0.x, w0.x); x[ 1] = make_float2(v0.y, w0.y);       \
    x[ 2] = make_float2(v0.z, w0.z); x[ 3] = make_float2(v0.w, w0.w);       \
    x[ 4] = make_float2(v1.x, w1.x); x[ 5] = make_float2(v1.y, w1.y);       \
    x[ 6] = make_float2(v1.z, w1.z); x[ 7] = make_float2(v1.w, w1.w);       \
    x[ 8] = make_float2(v2.x, w2.x); x[ 9] = make_float2(v2.y, w2.y);       \
    x[10] = make_float2(v2.z, w2.z); x[11] = make_float2(v2.w, w2.w);       \
    x[12] = make_float2(v3.x, w3.x); x[13] = make_float2(v3.y, w3.y);       \
    x[14] = make_float2(v3.z, w3.z); x[15] = make_float2(v3.w, w3.w);       \
} while (0)

// 12 butterfly levels + store for one element whose amps are in x[]
// (thread t owns idx = (t<<4)|r on entry). r2-verified index/bank patterns.
__device__ __forceinline__ void butterfly12_store(
    float2 (&x)[16], float2* __restrict__ L,
    const float (*__restrict__ g)[8], const int t, float2* __restrict__ o2)
{
    // stage A: idx bits 0..3 -> gates 11,10,9,8
    LEVEL(11, 0); LEVEL(10, 1); LEVEL(9, 2); LEVEL(8, 3);

    __syncthreads();    // LDS free of previous element's reads
#pragma unroll
    for (int k = 0; k < 8; ++k) {
        *(float4*)&L[PAD2((t << 4) | (2 * k))] =
            make_float4(x[2 * k].x, x[2 * k].y, x[2 * k + 1].x, x[2 * k + 1].y);
    }
    __syncthreads();
    const int base1 = ((t & 0xF0) << 4) | (t & 15);   // bits 11:8 | 3:0
#pragma unroll
    for (int r = 0; r < 16; ++r) x[r] = L[PAD2(base1 | (r << 4))];

    // stage B: idx bits 4..7 -> gates 7,6,5,4
    LEVEL(7, 0); LEVEL(6, 1); LEVEL(5, 2); LEVEL(4, 3);

    // write back to the SAME slots just read (no cross-thread WAR)
#pragma unroll
    for (int r = 0; r < 16; ++r) L[PAD2(base1 | (r << 4))] = x[r];
    __syncthreads();
#pragma unroll
    for (int r = 0; r < 16; ++r) x[r] = L[PAD2((r << 8) | t)];

    // stage C: idx bits 8..11 -> gates 3,2,1,0
    LEVEL(3, 0); LEVEL(2, 1); LEVEL(1, 2); LEVEL(0, 3);

    // store: idx = (r<<8)|t -> consecutive float2 across lanes
#pragma unroll
    for (int r = 0; r < 16; ++r) o2[(r << 8) | t] = x[r];
}

__global__ __launch_bounds__(256) void u3_pipe2_kernel(
    const float* __restrict__ thetas,   // [12,3]
    const float* __restrict__ sre,      // [512,4096]
    const float* __restrict__ sim_,     // [512,4096]
    float*       __restrict__ out)      // [512,4096,2]
{
    __shared__ __align__(16) float2 L[4608];     // PAD2(4095)+1 = 4606
    __shared__ __align__(16) float  g[NQ][8];

    const int blk = blockIdx.x;         // 0..255
    const int t   = threadIdx.x;
    const size_t e0 = 2 * (size_t)blk, e1 = e0 + 1;

    // ---- thetas load FIRST: its s_waitcnt then precedes the big loads
    //      in vmcnt order, so gate math doesn't drain the element loads ----
    float th = 0.f, ph = 0.f, la = 0.f;
    if (t < NQ) {
        th = thetas[3 * t + 0];
        ph = thetas[3 * t + 1];
        la = thetas[3 * t + 2];
    }

    // ---- issue e0 loads, then e1 loads (both in flight; in-order retire) ----
    const float4* pre0 = (const float4*)(sre  + e0 * DIM) + 4 * t;
    const float4* pim0 = (const float4*)(sim_ + e0 * DIM) + 4 * t;
    const float4* pre1 = (const float4*)(sre  + e1 * DIM) + 4 * t;
    const float4* pim1 = (const float4*)(sim_ + e1 * DIM) + 4 * t;
    float4 a0 = pre0[0], a1 = pre0[1], a2 = pre0[2], a3 = pre0[3];
    float4 b0 = pim0[0], b1 = pim0[1], b2 = pim0[2], b3 = pim0[3];
    float4 c0 = pre1[0], c1 = pre1[1], c2 = pre1[2], c3 = pre1[3];
    float4 d0 = pim1[0], d1 = pim1[1], d2 = pim1[2], d3 = pim1[3];

    // ---- gates (threads 0..11); gate q acts on state bit (11-q) ----
    if (t < NQ) {
        float c, s, cl, sl, cp, sp;
        __sincosf(th * 0.5f, &s, &c);
        __sincosf(la, &sl, &cl);
        __sincosf(ph, &sp, &cp);
        g[t][0] = c;        g[t][1] = 0.0f;
        g[t][2] = -cl * s;  g[t][3] = -sl * s;
        g[t][4] = cp * s;   g[t][5] = sp * s;
        g[t][6] = (cp * cl - sp * sl) * c;
        g[t][7] = (sp * cl + cp * sl) * c;
    }
    __syncthreads();    // gates visible

    float2 x[16];

    // ---- element 0: compute while e1's loads stream in ----
    UNPACK(a0, a1, a2, a3, b0, b1, b2, b3);
    butterfly12_store(x, L, g, t, (float2*)out + e0 * DIM);

    // ---- element 1: e0's stores drain underneath ----
    UNPACK(c0, c1, c2, c3, d0, d1, d2, d3);
    butterfly12_store(x, L, g, t, (float2*)out + e1 * DIM);
}

extern "C" void kernel_launch(void* const* d_in, const int* in_sizes, int n_in,
                              void* d_out, int out_size, void* d_ws, size_t ws_size,
                              hipStream_t stream) {
    const float* thetas = (const float*)d_in[0];
    const float* sre    = (const float*)d_in[1];
    const float* sim_   = (const float*)d_in[2];
    float* out = (float*)d_out;

    u3_pipe2_kernel<<<NBLK, 256, 0, stream>>>(thetas, sre, sim_, out);
}